// Round 1
// baseline (40.345 us; speedup 1.0000x reference)
//
#include <hip/hip_runtime.h>

#define NB 256
#define NN 128
#define E6 6

// ---------------------------------------------------------------------------
// Kernel A: M[e][a][m] = sum_n W_ext[e,m,n] * A_ext[a,n], e,a in [0,6)
// (e==0 or a==0 -> zeros). 36 blocks x 128 threads. Output: 36*128 floats.
// ---------------------------------------------------------------------------
__global__ __launch_bounds__(128) void precomp_M_kernel(
    const float* __restrict__ adj_w, const float* __restrict__ adj_a,
    float* __restrict__ M) {
  __shared__ __align__(16) float Wt[128][129];  // W transposed: Wt[n][m]
  __shared__ float As[128];
  const int e = blockIdx.x / E6;
  const int a = blockIdx.x % E6;
  const int t = threadIdx.x;
  float* outp = M + blockIdx.x * 128;
  if (e == 0 || a == 0) {
    outp[t] = 0.f;
    return;
  }
  As[t] = adj_a[(a - 1) * 128 + t];
  const float* W = adj_w + (size_t)(e - 1) * 128 * 128;
  // coalesced global read (lane = n), conflict-free LDS write (stride 129)
  for (int m = 0; m < 128; ++m) Wt[t][m] = W[m * 128 + t];
  __syncthreads();
  float acc = 0.f;
#pragma unroll 16
  for (int n = 0; n < 128; ++n) acc = fmaf(Wt[n][t], As[n], acc);
  outp[t] = acc;
}

// ---------------------------------------------------------------------------
// Main fused kernel: one block per batch b, 512 threads.
//   cnt[j][e]  = #{i : bfm[b,i,j]==e}           (register hist + LDS atomics)
//   msg[j][m]  = sum_e cnt[j][e]*M[e][a_bfm[b,j]][m]
//   out[b,i,m] = sum_j adj[b,i,j]*msg[j][m]     (8i x 4m register tile)
// ---------------------------------------------------------------------------
__global__ __launch_bounds__(512) void ggnn_fused_kernel(
    const int* __restrict__ bfm, const int* __restrict__ a_bfm,
    const float* __restrict__ adj, const float* __restrict__ M,
    float* __restrict__ out) {
  __shared__ __align__(16) float Ml[E6 * E6 * 128];  // 18 KB
  __shared__ __align__(16) float cntf[128][8];       // 4 KB
  __shared__ int aj[128];                            // 0.5 KB
  __shared__ __align__(16) float msg[128][128];      // 64 KB
  __shared__ __align__(16) float adjs[128][128];     // 64 KB

  const int b = blockIdx.x;
  const int tid = threadIdx.x;

  // --- stage adj[b] into registers early (latency hidden under hist phase) --
  float4 astage[8];
  {
    const float4* ap = (const float4*)(adj + (size_t)b * NN * NN);
#pragma unroll
    for (int r = 0; r < 8; ++r) astage[r] = ap[r * 512 + tid];
  }

  // --- load M table, a_bfm row, zero counters ---
  for (int idx = tid; idx < E6 * E6 * 128; idx += 512) Ml[idx] = M[idx];
  if (tid < 128) aj[tid] = a_bfm[b * NN + tid];
  ((float2*)cntf)[tid] = make_float2(0.f, 0.f);  // 1024 floats = 512 float2
  __syncthreads();

  // --- histogram phase: thread (q,j) counts i in [q*32, q*32+32) ---
  {
    const int j = tid & 127;
    const int q = tid >> 7;
    int c1 = 0, c2 = 0, c3 = 0, c4 = 0, c5 = 0;
    const int* bp = bfm + (size_t)b * NN * NN + (size_t)(q * 32) * NN + j;
#pragma unroll 8
    for (int i = 0; i < 32; ++i) {
      const int v = bp[i * NN];  // coalesced: lanes j consecutive
      c1 += (v == 1);
      c2 += (v == 2);
      c3 += (v == 3);
      c4 += (v == 4);
      c5 += (v == 5);
    }
    atomicAdd(&cntf[j][1], (float)c1);
    atomicAdd(&cntf[j][2], (float)c2);
    atomicAdd(&cntf[j][3], (float)c3);
    atomicAdd(&cntf[j][4], (float)c4);
    atomicAdd(&cntf[j][5], (float)c5);
  }
  __syncthreads();

  // --- messages phase: thread = (jg = tid>>5 owns 8 j's, mq = tid&31 owns 4 m's)
  {
    const int mq = tid & 31;
    const int jg = tid >> 5;
#pragma unroll
    for (int jj = 0; jj < 8; ++jj) {
      const int j = jg * 8 + jj;
      const int a = aj[j];
      const float c1 = cntf[j][1], c2 = cntf[j][2], c3 = cntf[j][3],
                  c4 = cntf[j][4], c5 = cntf[j][5];
      const float4 m1 = ((const float4*)(Ml + (1 * E6 + a) * 128))[mq];
      const float4 m2 = ((const float4*)(Ml + (2 * E6 + a) * 128))[mq];
      const float4 m3 = ((const float4*)(Ml + (3 * E6 + a) * 128))[mq];
      const float4 m4 = ((const float4*)(Ml + (4 * E6 + a) * 128))[mq];
      const float4 m5 = ((const float4*)(Ml + (5 * E6 + a) * 128))[mq];
      float4 r;
      r.x = c1 * m1.x + c2 * m2.x + c3 * m3.x + c4 * m4.x + c5 * m5.x;
      r.y = c1 * m1.y + c2 * m2.y + c3 * m3.y + c4 * m4.y + c5 * m5.y;
      r.z = c1 * m1.z + c2 * m2.z + c3 * m3.z + c4 * m4.z + c5 * m5.z;
      r.w = c1 * m1.w + c2 * m2.w + c3 * m3.w + c4 * m4.w + c5 * m5.w;
      ((float4*)&msg[j][0])[mq] = r;
    }
  }

  // --- write staged adj registers to LDS (vmcnt wait lands here) ---
  {
#pragma unroll
    for (int r = 0; r < 8; ++r) {
      ((float4*)&adjs[0][0])[r * 512 + tid] = astage[r];
    }
  }
  __syncthreads();

  // --- matmul: out[b] = adjs @ msg; thread owns 8 i x 4 m ---
  {
    const int tx = tid & 31;  // m = tx*4 .. tx*4+3
    const int ty = tid >> 5;  // i0 = ty*8
    const int i0 = ty * 8;
    float4 acc[8];
#pragma unroll
    for (int ii = 0; ii < 8; ++ii) acc[ii] = make_float4(0.f, 0.f, 0.f, 0.f);
#pragma unroll 4
    for (int j = 0; j < NN; ++j) {
      const float4 mv = ((const float4*)&msg[j][0])[tx];  // conflict-free
#pragma unroll
      for (int ii = 0; ii < 8; ++ii) {
        const float av = adjs[i0 + ii][j];  // 2-way broadcast: free
        acc[ii].x = fmaf(av, mv.x, acc[ii].x);
        acc[ii].y = fmaf(av, mv.y, acc[ii].y);
        acc[ii].z = fmaf(av, mv.z, acc[ii].z);
        acc[ii].w = fmaf(av, mv.w, acc[ii].w);
      }
    }
    float4* op = (float4*)(out + (size_t)b * NN * NN);
#pragma unroll
    for (int ii = 0; ii < 8; ++ii) op[(i0 + ii) * 32 + tx] = acc[ii];
  }
}

extern "C" void kernel_launch(void* const* d_in, const int* in_sizes, int n_in,
                              void* d_out, int out_size, void* d_ws,
                              size_t ws_size, hipStream_t stream) {
  // inputs: 0=afm(unused), 1=bfm, 2=a_bfm, 3=adj, 4=adj_w, 5=adj_a
  const int* bfm = (const int*)d_in[1];
  const int* a_bfm = (const int*)d_in[2];
  const float* adj = (const float*)d_in[3];
  const float* adj_w = (const float*)d_in[4];
  const float* adj_a = (const float*)d_in[5];
  float* out = (float*)d_out;
  float* M = (float*)d_ws;  // 36*128 floats = 18 KB scratch

  precomp_M_kernel<<<dim3(E6 * E6), dim3(128), 0, stream>>>(adj_w, adj_a, M);
  ggnn_fused_kernel<<<dim3(NB), dim3(512), 0, stream>>>(bfm, a_bfm, adj, M,
                                                        out);
}

// Round 2
// 36.245 us; speedup vs baseline: 1.1131x; 1.1131x over previous
//
#include <hip/hip_runtime.h>

#define NB 256
#define NN 128

typedef short s16x8 __attribute__((ext_vector_type(8)));
typedef float f32x4 __attribute__((ext_vector_type(4)));

__device__ __forceinline__ short f2bf(float f) {
  union { float f; unsigned u; } cv;
  cv.f = f;
  unsigned u = cv.u;
  u = (u + 0x7FFFu + ((u >> 16) & 1u)) >> 16;  // RNE
  return (short)u;
}

// ---------------------------------------------------------------------------
// Precompute Mc[e][a][m] = sum_n adj_w[e,m,n] * adj_a[a,n]   (e,a in [0,5))
// 5 blocks (one per e) x 128 threads (one per m). Output: 25*128 floats.
// ---------------------------------------------------------------------------
__global__ __launch_bounds__(128) void precomp_Mc(
    const float* __restrict__ adj_w, const float* __restrict__ adj_a,
    float* __restrict__ Mc) {
  __shared__ float As[5][128];
  const int t = threadIdx.x;
  const int e = blockIdx.x;  // 0..4
#pragma unroll
  for (int a = 0; a < 5; ++a) As[a][t] = adj_a[a * 128 + t];
  __syncthreads();
  const float* W = adj_w + (size_t)e * 16384 + (size_t)t * 128;  // row m=t
  float acc[5] = {0.f, 0.f, 0.f, 0.f, 0.f};
#pragma unroll 4
  for (int n = 0; n < 128; ++n) {
    const float wv = W[n];
#pragma unroll
    for (int a = 0; a < 5; ++a) acc[a] = fmaf(wv, As[a][n], acc[a]);
  }
#pragma unroll
  for (int a = 0; a < 5; ++a) Mc[(e * 5 + a) * 128 + t] = acc[a];
}

// ---------------------------------------------------------------------------
// Fused: one block per batch, 512 threads.
//   hist -> cnt[j][e]; msg[j][m] = sum_e cnt*M[e][a_j][m]  (f32 LDS);
//   out[b] = adj[b] @ msg  via bf16 MFMA 16x16x32 (f32 accumulate).
// ---------------------------------------------------------------------------
__global__ __launch_bounds__(512) void ggnn_fused_kernel(
    const int* __restrict__ bfm, const int* __restrict__ a_bfm,
    const float* __restrict__ adj, const float* __restrict__ Mc,
    float* __restrict__ out) {
  __shared__ __align__(16) float Ml[36 * 128];     // 18 KB  M[e6][a6][m]
  __shared__ __align__(16) float cntf[128][8];     // 4 KB
  __shared__ int aj[128];                          // 0.5 KB
  __shared__ __align__(16) float msg[128 * 128];   // 64 KB (f32, linear)
  __shared__ __align__(16) short adjs[128 * 128];  // 32 KB bf16, XOR-swizzled

  const int b = blockIdx.x;
  const int tid = threadIdx.x;

  // --- phase 0: zero counters only (cheap barrier: no VMEM pending) ---
  ((float2*)cntf)[tid] = make_float2(0.f, 0.f);
  __syncthreads();

  // --- phase 1: issue adj stage, histogram, table fills, adjs cvt+write ---
  float4 astage[8];
  {
    const float4* ap = (const float4*)(adj + (size_t)b * NN * NN);
#pragma unroll
    for (int r = 0; r < 8; ++r) astage[r] = ap[r * 512 + tid];
  }

  // histogram: thread (jq = tid&31 -> 4 j's, qq = tid>>5 -> 8 i's)
  const int jq = tid & 31;
  const int qq = tid >> 5;
  int cl[4][5];
#pragma unroll
  for (int jj = 0; jj < 4; ++jj)
#pragma unroll
    for (int e = 0; e < 5; ++e) cl[jj][e] = 0;
  {
    const int4* bp4 =
        (const int4*)(bfm + (size_t)b * NN * NN + (size_t)(qq * 8) * NN) + jq;
#pragma unroll
    for (int ii = 0; ii < 8; ++ii) {
      const int4 v = bp4[ii * 32];  // coalesced 512B per half-wave
      const int vv[4] = {v.x, v.y, v.z, v.w};
#pragma unroll
      for (int jj = 0; jj < 4; ++jj)
#pragma unroll
        for (int e = 0; e < 5; ++e) cl[jj][e] += (vv[jj] == (e + 1));
    }
  }

  // M table -> LDS (zeros for e==0 or a==0)
  for (int idx = tid; idx < 36 * 128; idx += 512) {
    const int row = idx >> 7;
    const int m = idx & 127;
    const int e6 = row / 6, a6 = row % 6;
    float v = 0.f;
    if (e6 >= 1 && a6 >= 1) v = Mc[((e6 - 1) * 5 + (a6 - 1)) * 128 + m];
    Ml[idx] = v;
  }
  if (tid < 128) aj[tid] = a_bfm[b * NN + tid];

  // adj f32 -> bf16, XOR-swizzled store (chunk16 ^= row&15)
#pragma unroll
  for (int r = 0; r < 8; ++r) {
    const int f = r * 512 + tid;
    const int row = f >> 5;     // i
    const int c4 = f & 31;      // float4 index within row
    const int chunk = c4 >> 1;  // 16B chunk (8 bf16)
    const int half = c4 & 1;
    short4 p;
    p.x = f2bf(astage[r].x);
    p.y = f2bf(astage[r].y);
    p.z = f2bf(astage[r].z);
    p.w = f2bf(astage[r].w);
    *(short4*)&adjs[row * 128 + ((chunk ^ (row & 15)) << 3) + (half << 2)] = p;
  }

#pragma unroll
  for (int jj = 0; jj < 4; ++jj)
#pragma unroll
    for (int e = 0; e < 5; ++e)
      atomicAdd(&cntf[jq * 4 + jj][e + 1], (float)cl[jj][e]);
  __syncthreads();

  // --- phase 2: messages (f32, natural layout, float4 writes) ---
  {
    const int mq = tid & 31;
    const int jg = tid >> 5;
#pragma unroll
    for (int jjj = 0; jjj < 8; ++jjj) {
      const int j = jg * 8 + jjj;
      const int a = aj[j];
      const float c1 = cntf[j][1], c2 = cntf[j][2], c3 = cntf[j][3],
                  c4v = cntf[j][4], c5 = cntf[j][5];
      const float4 m1 = ((const float4*)(Ml + (1 * 6 + a) * 128))[mq];
      const float4 m2 = ((const float4*)(Ml + (2 * 6 + a) * 128))[mq];
      const float4 m3 = ((const float4*)(Ml + (3 * 6 + a) * 128))[mq];
      const float4 m4 = ((const float4*)(Ml + (4 * 6 + a) * 128))[mq];
      const float4 m5 = ((const float4*)(Ml + (5 * 6 + a) * 128))[mq];
      float4 r;
      r.x = c1 * m1.x + c2 * m2.x + c3 * m3.x + c4v * m4.x + c5 * m5.x;
      r.y = c1 * m1.y + c2 * m2.y + c3 * m3.y + c4v * m4.y + c5 * m5.y;
      r.z = c1 * m1.z + c2 * m2.z + c3 * m3.z + c4v * m4.z + c5 * m5.z;
      r.w = c1 * m1.w + c2 * m2.w + c3 * m3.w + c4v * m4.w + c5 * m5.w;
      ((float4*)(msg + j * 128))[mq] = r;
    }
  }
  __syncthreads();

  // --- phase 3: MFMA matmul. Wave w owns cols [w*16, w*16+16), all 8 row
  // tiles -> zero B redundancy. K-loop: 4 steps of K=32. ---
  {
    const int w = tid >> 6;
    const int l = tid & 63;
    const int g = l >> 4;  // lane group (k-chunk)
    const int c = l & 15;  // col within tile / row within A-frag
    const int m0 = w * 16;
    f32x4 acc[8];
    const f32x4 zed = {0.f, 0.f, 0.f, 0.f};
#pragma unroll
    for (int rt = 0; rt < 8; ++rt) acc[rt] = zed;
#pragma unroll
    for (int kk = 0; kk < 4; ++kk) {
      s16x8 bfrag;
#pragma unroll
      for (int e = 0; e < 8; ++e)
        bfrag[e] = f2bf(msg[(kk * 32 + g * 8 + e) * 128 + m0 + c]);
#pragma unroll
      for (int rt = 0; rt < 8; ++rt) {
        const int row = rt * 16 + c;
        const s16x8 afrag =
            *(const s16x8*)&adjs[row * 128 + ((((kk << 2) + g) ^ c) << 3)];
        acc[rt] =
            __builtin_amdgcn_mfma_f32_16x16x32_bf16(afrag, bfrag, acc[rt], 0, 0, 0);
      }
    }
    float* ob = out + (size_t)b * NN * NN;
#pragma unroll
    for (int rt = 0; rt < 8; ++rt) {
      const int i = rt * 16 + g * 4;
#pragma unroll
      for (int q = 0; q < 4; ++q) ob[(i + q) * 128 + m0 + c] = acc[rt][q];
    }
  }
}

extern "C" void kernel_launch(void* const* d_in, const int* in_sizes, int n_in,
                              void* d_out, int out_size, void* d_ws,
                              size_t ws_size, hipStream_t stream) {
  // inputs: 0=afm(unused), 1=bfm, 2=a_bfm, 3=adj, 4=adj_w, 5=adj_a
  const int* bfm = (const int*)d_in[1];
  const int* a_bfm = (const int*)d_in[2];
  const float* adj = (const float*)d_in[3];
  const float* adj_w = (const float*)d_in[4];
  const float* adj_a = (const float*)d_in[5];
  float* out = (float*)d_out;
  float* Mc = (float*)d_ws;  // 25*128 floats = 12.8 KB scratch

  precomp_Mc<<<dim3(5), dim3(128), 0, stream>>>(adj_w, adj_a, Mc);
  ggnn_fused_kernel<<<dim3(NB), dim3(512), 0, stream>>>(bfm, a_bfm, adj, Mc,
                                                        out);
}

// Round 3
// 33.336 us; speedup vs baseline: 1.2102x; 1.0873x over previous
//
#include <hip/hip_runtime.h>

#define NN 128
#define NB 256

typedef short s16x8 __attribute__((ext_vector_type(8)));
typedef float f32x4 __attribute__((ext_vector_type(4)));

__device__ __forceinline__ short f2bf(float f) {
  union { float f; unsigned u; } cv;
  cv.f = f;
  unsigned u = cv.u;
  u = (u + 0x7FFFu + ((u >> 16) & 1u)) >> 16;  // RNE
  return (short)u;
}

// ---------------------------------------------------------------------------
// K0: Mc[(e*5+a)*128 + m] = sum_n adj_w[e,m,n] * adj_a[a,n].  5 blocks x 128.
// Coalesced: W transposed through LDS (lane = n on the global read).
// ---------------------------------------------------------------------------
__global__ __launch_bounds__(128) void precomp_Mc(
    const float* __restrict__ adj_w, const float* __restrict__ adj_a,
    float* __restrict__ Mc) {
  __shared__ float Wt[128][129];  // Wt[n][m]
  __shared__ float As[5][128];
  const int e = blockIdx.x, t = threadIdx.x;
#pragma unroll
  for (int a = 0; a < 5; ++a) As[a][t] = adj_a[a * 128 + t];
  const float* W = adj_w + (size_t)e * 16384;
  for (int m = 0; m < 128; ++m) Wt[t][m] = W[m * 128 + t];  // coalesced
  __syncthreads();
  float acc[5] = {0.f, 0.f, 0.f, 0.f, 0.f};
#pragma unroll 4
  for (int n = 0; n < 128; ++n) {
    const float wv = Wt[n][t];
#pragma unroll
    for (int a = 0; a < 5; ++a) acc[a] = fmaf(wv, As[a][n], acc[a]);
  }
#pragma unroll
  for (int a = 0; a < 5; ++a) Mc[(e * 5 + a) * 128 + t] = acc[a];
}

// ---------------------------------------------------------------------------
// K1: per (batch, 32-column group): histogram of bfm columns + msg compute.
// msg[b,j,m] (bf16) written to global PRE-SWIZZLED (16B chunk ^= (j>>3)&7)
// so K2 stages it linearly and reads B-fragments conflict-free.
// grid 1024 x 256 threads.
// ---------------------------------------------------------------------------
__global__ __launch_bounds__(256) void hist_msg_kernel(
    const int* __restrict__ bfm, const int* __restrict__ a_bfm,
    const float* __restrict__ Mc, short* __restrict__ msg_g) {
  __shared__ float Ml[25][132];   // 13.2 KB, padded stride (528B%128=16)
  __shared__ unsigned red[4][8][4][2];
  __shared__ uint2 cnt2[32];
  __shared__ int avs[32];

  const int b = blockIdx.x >> 2, jg = blockIdx.x & 3;
  const int t = threadIdx.x, w = t >> 6, l = t & 63;
  const int c4 = l & 7, rr = l >> 3;

  // Mc -> Ml (issued first so its waitcnt doesn't drain the bfm loads)
  for (int idx = t; idx < 3200; idx += 256) Ml[idx >> 7][idx & 127] = Mc[idx];
  if (t < 32) avs[t] = a_bfm[b * 128 + jg * 32 + t];

  // histogram: thread reads 4 int4 rows; counts packed in bytes
  const int4* bp = (const int4*)bfm + (size_t)b * 4096 + jg * 8 + c4;
  unsigned pA[4] = {0, 0, 0, 0}, pB[4] = {0, 0, 0, 0};
#pragma unroll
  for (int it = 0; it < 4; ++it) {
    const int i = it * 32 + w * 8 + rr;
    const int4 v = bp[(size_t)i * 32];
    const int vv[4] = {v.x, v.y, v.z, v.w};
#pragma unroll
    for (int jj = 0; jj < 4; ++jj) {
      pA[jj] += (unsigned)(vv[jj] == 1) + ((unsigned)(vv[jj] == 2) << 8) +
                ((unsigned)(vv[jj] == 3) << 16) + ((unsigned)(vv[jj] == 4) << 24);
      pB[jj] += (unsigned)(vv[jj] == 5);
    }
  }
  // reduce across the 8 lanes sharing c4 (byte sums <=32, no carry)
#pragma unroll
  for (int d = 8; d < 64; d <<= 1) {
#pragma unroll
    for (int jj = 0; jj < 4; ++jj) {
      pA[jj] += (unsigned)__shfl_xor((int)pA[jj], d);
      pB[jj] += (unsigned)__shfl_xor((int)pB[jj], d);
    }
  }
  if (rr == 0) {
#pragma unroll
    for (int jj = 0; jj < 4; ++jj) {
      red[w][c4][jj][0] = pA[jj];
      red[w][c4][jj][1] = pB[jj];
    }
  }
  __syncthreads();
  if (t < 32) {
    unsigned A = 0, B = 0;
    const int cc = t >> 2, jj = t & 3;
#pragma unroll
    for (int w2 = 0; w2 < 4; ++w2) {
      A += red[w2][cc][jj][0];
      B += red[w2][cc][jj][1];
    }
    cnt2[t] = make_uint2(A, B);  // byte sums <=128
  }
  __syncthreads();

  // msg: thread = (jl = t>>3, mq = t&7 -> 16 cols)
  {
    const int jl = t >> 3, mq = t & 7;
    const int jr = jg * 32 + jl;  // global j
    const uint2 cc = cnt2[jl];
    const int av = avs[jl];
    const float en = (av > 0) ? 1.f : 0.f;
    const int ai = (av > 0) ? (av - 1) : 0;
    const float c1 = en * (float)(cc.x & 255u);
    const float c2 = en * (float)((cc.x >> 8) & 255u);
    const float c3 = en * (float)((cc.x >> 16) & 255u);
    const float c4f = en * (float)(cc.x >> 24);
    const float c5 = en * (float)(cc.y & 255u);
    short* og = msg_g + (size_t)b * 16384 + jr * 128;
    const int swz = (jr >> 3) & 7;
#pragma unroll
    for (int ch = 0; ch < 2; ++ch) {
      const int chunk = mq * 2 + ch;  // 16B chunk (8 bf16) within the row
      s16x8 v8;
#pragma unroll
      for (int u4 = 0; u4 < 2; ++u4) {
        const int col4 = chunk * 2 + u4;
        const float4 m1 = ((const float4*)&Ml[ai][0])[col4];
        const float4 m2 = ((const float4*)&Ml[5 + ai][0])[col4];
        const float4 m3 = ((const float4*)&Ml[10 + ai][0])[col4];
        const float4 m4 = ((const float4*)&Ml[15 + ai][0])[col4];
        const float4 m5 = ((const float4*)&Ml[20 + ai][0])[col4];
        v8[u4 * 4 + 0] = f2bf(c1 * m1.x + c2 * m2.x + c3 * m3.x + c4f * m4.x + c5 * m5.x);
        v8[u4 * 4 + 1] = f2bf(c1 * m1.y + c2 * m2.y + c3 * m3.y + c4f * m4.y + c5 * m5.y);
        v8[u4 * 4 + 2] = f2bf(c1 * m1.z + c2 * m2.z + c3 * m3.z + c4f * m4.z + c5 * m5.z);
        v8[u4 * 4 + 3] = f2bf(c1 * m1.w + c2 * m2.w + c3 * m3.w + c4f * m4.w + c5 * m5.w);
      }
      *(s16x8*)&og[(chunk ^ swz) << 3] = v8;
    }
  }
}

// ---------------------------------------------------------------------------
// K2: out[b, r0:r0+64, :] = adj[b, r0:r0+64, :] @ msg[b]  (bf16 MFMA).
// grid 512 (b x half) x 256 threads, 48KB LDS -> 2 blocks/CU.
// ---------------------------------------------------------------------------
__global__ __launch_bounds__(256) void gemm_kernel(
    const float* __restrict__ adj, const short* __restrict__ msg_g,
    float* __restrict__ out) {
  __shared__ __align__(16) short adjs[64 * 128];   // 16 KB swizzled bf16
  __shared__ __align__(16) short msgs[128 * 128];  // 32 KB (content pre-swz)
  const int b = blockIdx.x >> 1, h = blockIdx.x & 1, r0 = h * 64;
  const int t = threadIdx.x;

  // adj half -> regs (issued first = oldest in vmcnt queue)
  float4 astage[8];
  const float4* ap = (const float4*)(adj + (size_t)b * 16384 + r0 * 128);
#pragma unroll
  for (int r = 0; r < 8; ++r) astage[r] = ap[r * 256 + t];

  // msg[b] -> regs (stays in flight while adj is converted)
  s16x8 mstage[8];
  const s16x8* mp = (const s16x8*)(msg_g + (size_t)b * 16384);
#pragma unroll
  for (int r = 0; r < 8; ++r) mstage[r] = mp[r * 256 + t];

  // adj cvt -> bf16, XOR-swizzled LDS (chunk ^= row&15); waits vmcnt(8)
#pragma unroll
  for (int r = 0; r < 8; ++r) {
    const int f = r * 256 + t;
    const int row = f >> 5, cc4 = f & 31;
    const int chunk = cc4 >> 1, half = cc4 & 1;
    short4 p;
    p.x = f2bf(astage[r].x);
    p.y = f2bf(astage[r].y);
    p.z = f2bf(astage[r].z);
    p.w = f2bf(astage[r].w);
    *(short4*)&adjs[row * 128 + ((chunk ^ (row & 15)) << 3) + (half << 2)] = p;
  }
  // msg -> LDS linear (content already swizzled)
#pragma unroll
  for (int r = 0; r < 8; ++r) *(s16x8*)&msgs[(r * 256 + t) * 8] = mstage[r];

  asm volatile("s_waitcnt lgkmcnt(0)" ::: "memory");
  __builtin_amdgcn_s_barrier();
  __builtin_amdgcn_sched_barrier(0);

  // GEMM: wave w owns cols w*32..+32 (2 col tiles) x 4 row tiles (64 rows)
  const int w = t >> 6, l = t & 63, g = l >> 4, c = l & 15;
  const int m0 = w * 32;
  f32x4 acc[4][2];
  const f32x4 zed = {0.f, 0.f, 0.f, 0.f};
#pragma unroll
  for (int rt = 0; rt < 4; ++rt) {
    acc[rt][0] = zed;
    acc[rt][1] = zed;
  }
#pragma unroll
  for (int kk = 0; kk < 4; ++kk) {
    s16x8 bfr[2];
#pragma unroll
    for (int ct = 0; ct < 2; ++ct) {
#pragma unroll
      for (int e = 0; e < 8; ++e) {
        const int k = kk * 32 + g * 8 + e;
        const int m = m0 + ct * 16 + c;
        bfr[ct][e] =
            msgs[k * 128 + (((m >> 3) ^ ((k >> 3) & 7)) << 3) + (m & 7)];
      }
    }
#pragma unroll
    for (int rt = 0; rt < 4; ++rt) {
      const int row = rt * 16 + c;
      const s16x8 afr =
          *(const s16x8*)&adjs[row * 128 + (((kk * 4 + g) ^ (row & 15)) << 3)];
#pragma unroll
      for (int ct = 0; ct < 2; ++ct)
        acc[rt][ct] = __builtin_amdgcn_mfma_f32_16x16x32_bf16(afr, bfr[ct],
                                                              acc[rt][ct], 0, 0, 0);
    }
  }
  float* ob = out + (size_t)b * 16384 + (size_t)r0 * 128;
#pragma unroll
  for (int rt = 0; rt < 4; ++rt)
#pragma unroll
    for (int ct = 0; ct < 2; ++ct)
#pragma unroll
      for (int q = 0; q < 4; ++q)
        ob[(rt * 16 + g * 4 + q) * 128 + m0 + ct * 16 + c] = acc[rt][ct][q];
}

extern "C" void kernel_launch(void* const* d_in, const int* in_sizes, int n_in,
                              void* d_out, int out_size, void* d_ws,
                              size_t ws_size, hipStream_t stream) {
  // inputs: 0=afm(unused), 1=bfm, 2=a_bfm, 3=adj, 4=adj_w, 5=adj_a
  const int* bfm = (const int*)d_in[1];
  const int* a_bfm = (const int*)d_in[2];
  const float* adj = (const float*)d_in[3];
  const float* adj_w = (const float*)d_in[4];
  const float* adj_a = (const float*)d_in[5];
  float* out = (float*)d_out;

  float* Mc = (float*)d_ws;                           // 3200 f32 = 12.8 KB
  short* msg_g = (short*)((char*)d_ws + 16384);       // 256*128*128 bf16 = 8.4 MB

  precomp_Mc<<<dim3(5), dim3(128), 0, stream>>>(adj_w, adj_a, Mc);
  hist_msg_kernel<<<dim3(1024), dim3(256), 0, stream>>>(bfm, a_bfm, Mc, msg_g);
  gemm_kernel<<<dim3(512), dim3(256), 0, stream>>>(adj, msg_g, out);
}

// Round 4
// 19.536 us; speedup vs baseline: 2.0651x; 1.7064x over previous
//
#include <hip/hip_runtime.h>

typedef short s16x8 __attribute__((ext_vector_type(8)));
typedef float f32x4 __attribute__((ext_vector_type(4)));

__device__ __forceinline__ short f2bf(float f) {  // RNE f32->bf16
  union { float f; unsigned u; } cv;
  cv.f = f;
  unsigned u = cv.u;
  u = (u + 0x7FFFu + ((u >> 16) & 1u)) >> 16;
  return (short)u;
}
// pack two f32 -> bf16x2 by truncation (low elem = lo)
__device__ __forceinline__ unsigned pk2(float lo, float hi) {
  union { float f; unsigned u; } a, b;
  a.f = lo;
  b.f = hi;
  return (a.u >> 16) | (b.u & 0xFFFF0000u);
}

// ---------------------------------------------------------------------------
// K1: blocks 0..1023 = histogram (b, 32-col group) -> cnt_g (byte-packed).
//     blocks 1024..1043 = Mc table: Mc_bf[(e*5+a)*128+m] = sum_n W[e,m,n]A[a,n]
// ---------------------------------------------------------------------------
__global__ __launch_bounds__(256, 4) void hist_mc_kernel(
    const int* __restrict__ bfm, const float* __restrict__ adj_w,
    const float* __restrict__ adj_a, uint2* __restrict__ cnt_g,
    unsigned short* __restrict__ Mc_bf) {
  __shared__ unsigned red[4][8][4][2];
  __shared__ float As[5][128];
  const int t = threadIdx.x;

  if (blockIdx.x >= 1024) {  // ---- Mc blocks ----
    const int bi = blockIdx.x - 1024;
    const int e = bi >> 2, mg = bi & 3;
    for (int idx = t; idx < 640; idx += 256) As[idx >> 7][idx & 127] = adj_a[idx];
    __syncthreads();
    const int m = mg * 32 + (t >> 3), ns = t & 7;
    const float* W = adj_w + (size_t)e * 16384 + (size_t)m * 128 + ns * 16;
    float acc[5] = {0.f, 0.f, 0.f, 0.f, 0.f};
#pragma unroll
    for (int it = 0; it < 4; ++it) {
      const float4 wv = *(const float4*)(W + it * 4);
      const float wa[4] = {wv.x, wv.y, wv.z, wv.w};
#pragma unroll
      for (int q = 0; q < 4; ++q) {
        const int n = ns * 16 + it * 4 + q;
#pragma unroll
        for (int a = 0; a < 5; ++a) acc[a] = fmaf(wa[q], As[a][n], acc[a]);
      }
    }
#pragma unroll
    for (int d = 1; d < 8; d <<= 1)
#pragma unroll
      for (int a = 0; a < 5; ++a) acc[a] += __shfl_xor(acc[a], d);
    if (ns == 0)
#pragma unroll
      for (int a = 0; a < 5; ++a)
        Mc_bf[(e * 5 + a) * 128 + m] = (unsigned short)f2bf(acc[a]);
    return;
  }

  // ---- hist blocks ----
  const int b = blockIdx.x >> 2, jg = blockIdx.x & 3;
  const int w = t >> 6, l = t & 63, c4 = l & 7, rr = l >> 3;
  const int4* bp = (const int4*)bfm + (size_t)b * 4096 + jg * 8 + c4;
  unsigned pA[4] = {0, 0, 0, 0}, pB[4] = {0, 0, 0, 0};
#pragma unroll
  for (int it = 0; it < 4; ++it) {
    const int i = it * 32 + w * 8 + rr;
    const int4 v = bp[(size_t)i * 32];
    const int vv[4] = {v.x, v.y, v.z, v.w};
#pragma unroll
    for (int jj = 0; jj < 4; ++jj) {
      pA[jj] += (unsigned)(vv[jj] == 1) + ((unsigned)(vv[jj] == 2) << 8) +
                ((unsigned)(vv[jj] == 3) << 16) + ((unsigned)(vv[jj] == 4) << 24);
      pB[jj] += (unsigned)(vv[jj] == 5);
    }
  }
#pragma unroll
  for (int d = 8; d < 64; d <<= 1)
#pragma unroll
    for (int jj = 0; jj < 4; ++jj) {
      pA[jj] += (unsigned)__shfl_xor((int)pA[jj], d);
      pB[jj] += (unsigned)__shfl_xor((int)pB[jj], d);
    }
  if (rr == 0)
#pragma unroll
    for (int jj = 0; jj < 4; ++jj) {
      red[w][c4][jj][0] = pA[jj];
      red[w][c4][jj][1] = pB[jj];
    }
  __syncthreads();
  if (t < 32) {
    unsigned A = 0, B = 0;
    const int cc = t >> 2, jj = t & 3;
#pragma unroll
    for (int w2 = 0; w2 < 4; ++w2) {
      A += red[w2][cc][jj][0];
      B += red[w2][cc][jj][1];
    }
    cnt_g[b * 128 + jg * 32 + t] = make_uint2(A, B);
  }
}

// ---------------------------------------------------------------------------
// K2: per (b, row-half). msgsT = (P @ Mtab)^T via MFMA (transpose free from
// C-layout), then out-half = adj-half @ msg via MFMA with A loaded from
// global at T=0 (hidden under msg phase) and B = conflict-free b128 reads.
// ---------------------------------------------------------------------------
__global__ __launch_bounds__(256, 3) void fused_gemm_kernel(
    const float* __restrict__ adj, const int* __restrict__ a_bfm,
    const uint2* __restrict__ cnt_g, const unsigned short* __restrict__ Mc_bf,
    float* __restrict__ out) {
  __shared__ __align__(16) unsigned short msgsT[128 * 128];  // [m][j] swz 32KB
  __shared__ __align__(16) unsigned short P[128 * 40];       // [j][r] 10KB
  __shared__ __align__(16) unsigned short Mtab[32 * 136];    // [r][m] 8.5KB
  const int b = blockIdx.x >> 1, h = blockIdx.x & 1, r0 = h * 64;
  const int t = threadIdx.x;
  const int w = t >> 6, l = t & 63, g = l >> 4, c = l & 15;

  // ---- A-panel loads at T=0 (wave w owns rows r0+w*16..+16; lane row = +c)
  const float* arow = adj + (size_t)b * 16384 + (size_t)(r0 + w * 16 + c) * 128;
  float4 a0[4], a1[4];
#pragma unroll
  for (int kk = 0; kk < 4; ++kk) {
    a0[kk] = *(const float4*)(arow + (kk * 4 + g) * 8);
    a1[kk] = *(const float4*)(arow + (kk * 4 + g) * 8 + 4);
  }

  // ---- cnt/aj ----
  unsigned cA = 0, cB = 0;
  int av = 0;
  if (t < 128) {
    const uint2 cc2 = cnt_g[b * 128 + t];
    cA = cc2.x;
    cB = cc2.y;
    av = a_bfm[b * 128 + t];
  }
  // ---- Mtab load (+zero pad rows), P zero ----
  for (int idx = t; idx < 400; idx += 256) {
    const int row = idx >> 4, c8 = idx & 15;
    *(s16x8*)&Mtab[row * 136 + c8 * 8] = *(const s16x8*)&Mc_bf[row * 128 + c8 * 8];
  }
  for (int idx = t; idx < 7 * 136; idx += 256) Mtab[25 * 136 + idx] = 0;
  for (int idx = t; idx < 640; idx += 256)
    ((uint4*)P)[idx] = make_uint4(0u, 0u, 0u, 0u);
  __syncthreads();

  // ---- scatter P: P[j][(e-1)*5+ai] = cnt_e (bf16-exact, <=128) ----
  if (t < 128 && av > 0) {
    const int ai = av - 1;
    unsigned short* Pr = &P[t * 40];
    Pr[ai] = (unsigned short)f2bf((float)(cA & 255u));
    Pr[5 + ai] = (unsigned short)f2bf((float)((cA >> 8) & 255u));
    Pr[10 + ai] = (unsigned short)f2bf((float)((cA >> 16) & 255u));
    Pr[15 + ai] = (unsigned short)f2bf((float)(cA >> 24));
    Pr[20 + ai] = (unsigned short)f2bf((float)(cB & 255u));
  }
  __syncthreads();

  // ---- msg MFMA: wave w -> m-strip [w*32,+32). C-layout writes msgsT. ----
  {
    const int m0 = w * 32;
    s16x8 bfr[2];
#pragma unroll
    for (int ct = 0; ct < 2; ++ct)
#pragma unroll
      for (int e = 0; e < 8; ++e)
        bfr[ct][e] = (short)Mtab[(g * 8 + e) * 136 + m0 + ct * 16 + c];
#pragma unroll
    for (int jt = 0; jt < 8; ++jt) {
      const s16x8 afr = *(const s16x8*)&P[(jt * 16 + c) * 40 + g * 8];
#pragma unroll
      for (int ct = 0; ct < 2; ++ct) {
        f32x4 acc = {0.f, 0.f, 0.f, 0.f};
        acc = __builtin_amdgcn_mfma_f32_16x16x32_bf16(afr, bfr[ct], acc, 0, 0, 0);
        const int m = m0 + ct * 16 + c;
        // j = jt*16 + g*4 + q -> chunk = jt*2+(g>>1), elem = (g&1)*4+q
        unsigned short* dst =
            &msgsT[m * 128 + (((jt * 2 + (g >> 1)) ^ (m & 15)) << 3) + (g & 1) * 4];
#pragma unroll
        for (int q = 0; q < 4; ++q) dst[q] = (unsigned short)f2bf(acc[q]);
      }
    }
  }

  // ---- pack A (vmcnt waits land here; loads issued ~2K cycles ago) ----
  s16x8 apk[4];
#pragma unroll
  for (int kk = 0; kk < 4; ++kk) {
    unsigned* pu = (unsigned*)&apk[kk];
    pu[0] = pk2(a0[kk].x, a0[kk].y);
    pu[1] = pk2(a0[kk].z, a0[kk].w);
    pu[2] = pk2(a1[kk].x, a1[kk].y);
    pu[3] = pk2(a1[kk].z, a1[kk].w);
  }
  __syncthreads();

  // ---- GEMM2: wave w -> rows [r0+w*16,+16), all 128 m. Zero VMEM. ----
  f32x4 acc2[8];
#pragma unroll
  for (int mt = 0; mt < 8; ++mt) acc2[mt] = (f32x4){0.f, 0.f, 0.f, 0.f};
#pragma unroll
  for (int kk = 0; kk < 4; ++kk) {
#pragma unroll
    for (int mt = 0; mt < 8; ++mt) {
      const int m = mt * 16 + c;
      const s16x8 bfr2 =
          *(const s16x8*)&msgsT[m * 128 + (((kk * 4 + g) ^ (m & 15)) << 3)];
      acc2[mt] = __builtin_amdgcn_mfma_f32_16x16x32_bf16(apk[kk], bfr2, acc2[mt], 0, 0, 0);
    }
  }
  float* ob = out + (size_t)b * 16384 + (size_t)(r0 + w * 16) * 128;
#pragma unroll
  for (int mt = 0; mt < 8; ++mt)
#pragma unroll
    for (int q = 0; q < 4; ++q)
      ob[(g * 4 + q) * 128 + mt * 16 + c] = acc2[mt][q];
}

extern "C" void kernel_launch(void* const* d_in, const int* in_sizes, int n_in,
                              void* d_out, int out_size, void* d_ws,
                              size_t ws_size, hipStream_t stream) {
  // inputs: 0=afm(unused), 1=bfm, 2=a_bfm, 3=adj, 4=adj_w, 5=adj_a
  const int* bfm = (const int*)d_in[1];
  const int* a_bfm = (const int*)d_in[2];
  const float* adj = (const float*)d_in[3];
  const float* adj_w = (const float*)d_in[4];
  const float* adj_a = (const float*)d_in[5];
  float* out = (float*)d_out;

  unsigned short* Mc_bf = (unsigned short*)d_ws;          // 25*128 bf16 = 6.4KB
  uint2* cnt_g = (uint2*)((char*)d_ws + 8192);            // 256*128*8B = 256KB

  hist_mc_kernel<<<dim3(1044), dim3(256), 0, stream>>>(bfm, adj_w, adj_a,
                                                       cnt_g, Mc_bf);
  fused_gemm_kernel<<<dim3(512), dim3(256), 0, stream>>>(adj, a_bfm, cnt_g,
                                                         Mc_bf, out);
}